// Round 3
// baseline (3130.673 us; speedup 1.0000x reference)
//
#include <hip/hip_runtime.h>
#include <hip/hip_fp16.h>

// A-SNN forward: B=64, T=512, I=O=1024, A=3.
// Plan:
//   init_weights: fp32->fp16 weight images (W1 for input GEMM, W2 padded rows for scan LDS)
//   gemm1:  XW[t*64+b][0:2048] = x @ [ww_x;wb_x]^T + [bw;bb]   (MFMA 16x16x32 f16, 128x128 tile)
//   xa_proj: XA[t*64+b][0:3] = x @ wa_x^T + ba                 (wave-per-row dot)
//   scan_kernel: 256 persistent WGs = 8 batch-domains x 32 col-groups; recurrent weights live
//                in LDS; 1 domain-sync per step via agent-scope atomics (coherent, cache-bypass).

#define B_ 64
#define T_ 512
#define I_ 1024
#define O_ 1024

typedef __attribute__((ext_vector_type(8))) _Float16 half8;
typedef __attribute__((ext_vector_type(4))) float f32x4;
typedef __attribute__((ext_vector_type(4))) float float4v;
typedef __attribute__((ext_vector_type(4))) unsigned int uint4v;

__device__ __forceinline__ float sigm_f(float x) { return 1.f / (1.f + __expf(-x)); }
__device__ __forceinline__ float tanh_f(float x) { return 1.f - 2.f / (1.f + __expf(2.f * x)); }

// ---------------- workspace layout (bytes) ----------------
#define WS_XW    0                 // [32768][2048] f16 = 134,217,728
#define WS_W1    134217728         // [2048][1024]  f16 = 4,194,304
#define WS_W2    138412032         // [2][1024][1032] f16 = 4,227,072 (padded rows)
#define WS_XA    142639104         // [32768][3] f32 = 393,216
#define WS_HBUF  143032320         // [2][64][1024] f16 (as uint[2][64][512]) = 262,144
#define WS_PART  143294464         // [2][8][8][32][4] f32 = 131,072
#define WS_CNT   143425536         // [8][64] u32 = 2,048
#define WS_END   143427584

// ---------------- scan LDS layout ----------------
#define WLDS_OFF 0                 // [2][32][1032] f16 = 132,096
#define HLDS_OFF 132096            // [8][1032] f16 = 16,512
#define ROWB     2064              // padded row bytes (1032 halves)
#define ZBLK_OFF 148608            // 16B zero block
#define GBUF_OFF 148624            // [2][8][32] f32 = 2,048
#define SMEM_BYTES 150784

// ======================= init: weight conversion =======================
__global__ void init_weights(const float* __restrict__ ww_x, const float* __restrict__ wb_x,
                             const float* __restrict__ ww_y, const float* __restrict__ wb_y,
                             _Float16* __restrict__ W1, _Float16* __restrict__ W2) {
    const int total1 = 2048 * 1024;
    const int total2 = 2 * 1024 * 1032;
    for (int idx = blockIdx.x * blockDim.x + threadIdx.x; idx < total1 + total2;
         idx += gridDim.x * blockDim.x) {
        if (idx < total1) {
            int n = idx >> 10, i = idx & 1023;
            float v = (n < 1024) ? ww_x[n * 1024 + i] : wb_x[(n - 1024) * 1024 + i];
            W1[idx] = (_Float16)v;
        } else {
            int j = idx - total1;
            int mat = j / (1024 * 1032);
            int rem = j - mat * (1024 * 1032);
            int row = rem / 1032, col = rem - row * 1032;
            float v = 0.f;
            if (col < 1024) v = (mat ? wb_y : ww_y)[row * 1024 + col];
            W2[j] = (_Float16)v;
        }
    }
}

// ======================= gemm1: input projections =======================
// C[m][n] = sum_k x_row(m)[k] * W1[n][k] + bias(n), m = t*64+b, stored fp16.
__global__ __launch_bounds__(256) void gemm1(const float* __restrict__ x,
                                             const _Float16* __restrict__ W1,
                                             const float* __restrict__ bw,
                                             const float* __restrict__ bb,
                                             _Float16* __restrict__ XW) {
    __shared__ _Float16 At[2][128][40];  // 32 k + 8 pad
    __shared__ _Float16 Bt[2][128][40];
    const int tid = threadIdx.x;
    const int lane = tid & 63, wid = tid >> 6;
    const int wr = wid >> 1, wc = wid & 1;
    const int ntile = blockIdx.x & 15;
    const int mtile = blockIdx.x >> 4;
    const long m0 = (long)mtile * 128;
    const int n0 = ntile * 128;

    const int r = tid >> 1, hf = tid & 1;
    const int bidx = (int)((m0 + r) & 63);
    const int tt = (int)((m0 + r) >> 6);
    const float* xrow = x + ((size_t)bidx * T_ + tt) * I_ + hf * 16;
    const _Float16* brow = W1 + (size_t)(n0 + r) * 1024 + hf * 16;

    float4v av[4];
    uint4v bv[2];
    auto stage_regs = [&](int kt) {
        const float4v* pa = (const float4v*)(xrow + kt * 32);
        av[0] = pa[0]; av[1] = pa[1]; av[2] = pa[2]; av[3] = pa[3];
        const uint4v* pb = (const uint4v*)(brow + kt * 32);
        bv[0] = pb[0]; bv[1] = pb[1];
    };
    auto write_lds = [&](int buf) {
        union { _Float16 h[16]; half8 v[2]; } u;
        #pragma unroll
        for (int q = 0; q < 4; ++q)
            #pragma unroll
            for (int c = 0; c < 4; ++c) u.h[q * 4 + c] = (_Float16)av[q][c];
        half8* dA = (half8*)&At[buf][r][hf * 16];
        dA[0] = u.v[0]; dA[1] = u.v[1];
        uint4v* dB = (uint4v*)&Bt[buf][r][hf * 16];
        dB[0] = bv[0]; dB[1] = bv[1];
    };

    f32x4 acc[4][4];
    #pragma unroll
    for (int i = 0; i < 4; ++i)
        #pragma unroll
        for (int j = 0; j < 4; ++j) acc[i][j] = (f32x4){0.f, 0.f, 0.f, 0.f};

    const int frow = lane & 15, fch = lane >> 4;
    auto compute = [&](int buf) {
        half8 a[4], b[4];
        #pragma unroll
        for (int i = 0; i < 4; ++i)
            a[i] = *(const half8*)&At[buf][wr * 64 + i * 16 + frow][fch * 8];
        #pragma unroll
        for (int j = 0; j < 4; ++j)
            b[j] = *(const half8*)&Bt[buf][wc * 64 + j * 16 + frow][fch * 8];
        #pragma unroll
        for (int i = 0; i < 4; ++i)
            #pragma unroll
            for (int j = 0; j < 4; ++j)
                acc[i][j] = __builtin_amdgcn_mfma_f32_16x16x32_f16(a[i], b[j], acc[i][j], 0, 0, 0);
    };

    stage_regs(0);
    write_lds(0);
    __syncthreads();
    for (int kt = 0; kt < 32; ++kt) {
        const int cur = kt & 1;
        if (kt < 31) stage_regs(kt + 1);
        compute(cur);
        if (kt < 31) { write_lds(cur ^ 1); __syncthreads(); }
    }

    const int orow = (lane >> 4) * 4, ocol = lane & 15;
    #pragma unroll
    for (int j = 0; j < 4; ++j) {
        const int n = n0 + wc * 64 + j * 16 + ocol;
        const float bias = (n < 1024) ? bw[n] : bb[n - 1024];
        #pragma unroll
        for (int i = 0; i < 4; ++i) {
            const long mb = m0 + wr * 64 + i * 16 + orow;
            #pragma unroll
            for (int rr = 0; rr < 4; ++rr)
                XW[(size_t)(mb + rr) * 2048 + n] = (_Float16)(acc[i][j][rr] + bias);
        }
    }
}

// ======================= xa projection =======================
__global__ __launch_bounds__(256) void xa_proj(const float* __restrict__ x,
                                               const float* __restrict__ wa_x,
                                               const float* __restrict__ ba,
                                               float* __restrict__ XA) {
    const int wid = threadIdx.x >> 6, lane = threadIdx.x & 63;
    const long m = (long)blockIdx.x * 4 + wid;
    const int b = (int)(m & 63), t = (int)(m >> 6);
    const float4v* xr = (const float4v*)(x + ((size_t)b * T_ + t) * I_);
    const float4v* w0 = (const float4v*)(wa_x);
    const float4v* w1 = (const float4v*)(wa_x + 1024);
    const float4v* w2 = (const float4v*)(wa_x + 2048);
    float a0 = 0.f, a1 = 0.f, a2 = 0.f;
    #pragma unroll
    for (int j = 0; j < 4; ++j) {
        const int idx = j * 64 + lane;
        float4v xv = xr[idx];
        float4v v0 = w0[idx], v1 = w1[idx], v2 = w2[idx];
        a0 += xv[0] * v0[0] + xv[1] * v0[1] + xv[2] * v0[2] + xv[3] * v0[3];
        a1 += xv[0] * v1[0] + xv[1] * v1[1] + xv[2] * v1[2] + xv[3] * v1[3];
        a2 += xv[0] * v2[0] + xv[1] * v2[1] + xv[2] * v2[2] + xv[3] * v2[3];
    }
    #pragma unroll
    for (int mset = 32; mset >= 1; mset >>= 1) {
        a0 += __shfl_xor(a0, mset);
        a1 += __shfl_xor(a1, mset);
        a2 += __shfl_xor(a2, mset);
    }
    if (lane == 0) {
        XA[m * 3 + 0] = a0 + ba[0];
        XA[m * 3 + 1] = a1 + ba[1];
        XA[m * 3 + 2] = a2 + ba[2];
    }
}

// ======================= scan =======================
__global__ __launch_bounds__(256, 1) void scan_kernel(
    const _Float16* __restrict__ XW, const float* __restrict__ XA,
    const _Float16* __restrict__ W2, const float* __restrict__ wa_y,
    float* __restrict__ out, float* __restrict__ yfin,
    unsigned int* Hbuf, float* PART, unsigned int* CNT) {
    extern __shared__ char smem[];
    const int tid = threadIdx.x;
    const int lane = tid & 63;
    const int wid = tid >> 6;
    const int d = blockIdx.x & 7;    // batch domain (8 batches)
    const int g = blockIdx.x >> 3;   // column group (32 cols)
    const int n0 = g * 32;
    const int b0 = d * 8;
    const int bl = tid >> 5;         // local batch 0..7
    const int nn = tid & 31;         // local col 0..31
    const int bg = b0 + bl;
    const int ng = n0 + nn;

    // persistent recurrent weights -> LDS
    {
        const uint4v* src = (const uint4v*)W2;
        uint4v* dst = (uint4v*)(smem + WLDS_OFF);
        for (int idx = tid; idx < 2 * 4128; idx += 256) {
            const int mat = idx / 4128;
            const int c = idx - mat * 4128;
            dst[idx] = src[(size_t)(mat * 1024 + n0) * 129 + c];
        }
        if (tid == 0) *(uint4v*)(smem + ZBLK_OFF) = (uint4v){0u, 0u, 0u, 0u};
    }
    const float way0 = wa_y[ng];
    const float way1 = wa_y[1024 + ng];
    const float way2 = wa_y[2048 + ng];
    __syncthreads();

    const int mat = wid >> 1, ntile = wid & 1;
    const int frow = lane & 15, fch = lane >> 4;
    const int a_base = (frow < 8) ? (HLDS_OFF + frow * ROWB + fch * 16) : ZBLK_OFF;
    const int a_step = (frow < 8) ? 64 : 0;
    const int b_base = WLDS_OFF + (mat * 32 + ntile * 16 + frow) * ROWB + fch * 16;

    float* gbuf = (float*)(smem + GBUF_OFF);
    unsigned long long* H64 = (unsigned long long*)Hbuf;

    float y = 0.f;
    for (int t = 0; t < T_; ++t) {
        // gate inputs (independent of other WGs) — issue before the sync to hide latency
        const size_t mrow = (size_t)t * 64 + bg;
        const float xwv = (float)XW[mrow * 2048 + ng];
        const float xbv = (float)XW[mrow * 2048 + 1024 + ng];
        const float xa0 = XA[mrow * 3 + 0];
        const float xa1 = XA[mrow * 3 + 1];
        const float xa2 = XA[mrow * 3 + 2];

        if (t > 0) {
            if (tid == 0) {
                const unsigned int target = 32u * (unsigned int)t;
                while (__hip_atomic_load(&CNT[d * 64], __ATOMIC_RELAXED,
                                         __HIP_MEMORY_SCOPE_AGENT) < target) {}
            }
            __syncthreads();
        }

        float pa0 = 0.f, pa1 = 0.f, pa2 = 0.f;
        if (t > 0) {
            const int par = (t - 1) & 1;
            unsigned long long hv[8];
            #pragma unroll
            for (int it = 0; it < 8; ++it) {
                const int c = nn + it * 32;
                hv[it] = __hip_atomic_load(&H64[((size_t)par * 64 + bg) * 256 + c],
                                           __ATOMIC_RELAXED, __HIP_MEMORY_SCOPE_AGENT);
            }
            #pragma unroll
            for (int it = 0; it < 8; ++it) {
                const int c = nn + it * 32;
                *(unsigned long long*)(smem + HLDS_OFF + bl * ROWB + c * 8) = hv[it];
            }
            float* pp = PART + ((((size_t)par * 8 + d) * 8 + bl) * 32 + nn) * 4;
            pa0 = __hip_atomic_load(pp + 0, __ATOMIC_RELAXED, __HIP_MEMORY_SCOPE_AGENT);
            pa1 = __hip_atomic_load(pp + 1, __ATOMIC_RELAXED, __HIP_MEMORY_SCOPE_AGENT);
            pa2 = __hip_atomic_load(pp + 2, __ATOMIC_RELAXED, __HIP_MEMORY_SCOPE_AGENT);
            #pragma unroll
            for (int mset = 16; mset >= 1; mset >>= 1) {
                pa0 += __shfl_xor(pa0, mset);
                pa1 += __shfl_xor(pa1, mset);
                pa2 += __shfl_xor(pa2, mset);
            }
        } else {
            #pragma unroll
            for (int it = 0; it < 8; ++it) {
                const int c = nn + it * 32;
                *(unsigned long long*)(smem + HLDS_OFF + bl * ROWB + c * 8) = 0ull;
            }
        }
        __syncthreads();

        // g = h_{t-1} @ W^T for this (matrix, ntile)
        f32x4 acc = (f32x4){0.f, 0.f, 0.f, 0.f};
        {
            int ao = a_base, bo = b_base;
            #pragma unroll 8
            for (int kt = 0; kt < 32; ++kt) {
                half8 av = *(const half8*)(smem + ao);
                half8 bvv = *(const half8*)(smem + bo);
                acc = __builtin_amdgcn_mfma_f32_16x16x32_f16(av, bvv, acc, 0, 0, 0);
                ao += a_step; bo += 64;
            }
        }
        if (lane < 32) {
            const int brow = (lane >> 4) * 4;
            const int col = lane & 15;
            float* gb = gbuf + (mat * 8) * 32 + ntile * 16 + col;
            gb[(brow + 0) * 32] = acc[0];
            gb[(brow + 1) * 32] = acc[1];
            gb[(brow + 2) * 32] = acc[2];
            gb[(brow + 3) * 32] = acc[3];
        }
        __syncthreads();

        const float gw = gbuf[bl * 32 + nn];
        const float gb2 = gbuf[(8 + bl) * 32 + nn];
        const float wv = sigm_f(xwv + gw);
        const float bgt = tanh_f(xbv + gb2);
        const float wa0 = sigm_f(xa0 + pa0);
        const float wa1 = sigm_f(xa1 + pa1);
        const float wa2 = sigm_f(xa2 + pa2);
        y = wv * y + bgt;
        y = (y >= 0.f) ? y : 0.01f * y;
        const float th = tanh_f(y);
        const float sp = (y > 20.f) ? y : __logf(1.f + __expf(y));
        const float h = tanh_f(0.1f * (y * wa0 + th * wa1 + sp * wa2));

        out[((size_t)bg * T_ + t) * O_ + ng] = h;

        _Float16 hh = (_Float16)h;
        unsigned int hu = (unsigned int)*(unsigned short*)&hh;
        const unsigned int hpart = __shfl_xor(hu, 1);
        if ((nn & 1) == 0) {
            const unsigned int packed = hu | (hpart << 16);
            __hip_atomic_store(&Hbuf[((size_t)(t & 1) * 64 + bg) * 512 + (ng >> 1)], packed,
                               __ATOMIC_RELAXED, __HIP_MEMORY_SCOPE_AGENT);
        }
        float p0 = h * way0, p1 = h * way1, p2 = h * way2;
        #pragma unroll
        for (int mset = 16; mset >= 1; mset >>= 1) {
            p0 += __shfl_xor(p0, mset);
            p1 += __shfl_xor(p1, mset);
            p2 += __shfl_xor(p2, mset);
        }
        if (nn == 0) {
            float* pp = PART + ((((size_t)(t & 1) * 8 + d) * 8 + bl) * 32 + g) * 4;
            __hip_atomic_store(pp + 0, p0, __ATOMIC_RELAXED, __HIP_MEMORY_SCOPE_AGENT);
            __hip_atomic_store(pp + 1, p1, __ATOMIC_RELAXED, __HIP_MEMORY_SCOPE_AGENT);
            __hip_atomic_store(pp + 2, p2, __ATOMIC_RELAXED, __HIP_MEMORY_SCOPE_AGENT);
        }
        __builtin_amdgcn_s_waitcnt(0);
        __syncthreads();  // drains all waves' stores before the arrival
        if (tid == 0)
            __hip_atomic_fetch_add(&CNT[d * 64], 1u, __ATOMIC_RELAXED, __HIP_MEMORY_SCOPE_AGENT);
    }
    yfin[(size_t)bg * O_ + ng] = y;
}

// ======================= launch =======================
extern "C" void kernel_launch(void* const* d_in, const int* in_sizes, int n_in,
                              void* d_out, int out_size, void* d_ws, size_t ws_size,
                              hipStream_t stream) {
    const float* x    = (const float*)d_in[0];
    const float* ww_x = (const float*)d_in[1];
    const float* ww_y = (const float*)d_in[2];
    const float* bw   = (const float*)d_in[3];
    const float* wb_x = (const float*)d_in[4];
    const float* wb_y = (const float*)d_in[5];
    const float* bb   = (const float*)d_in[6];
    const float* wa_x = (const float*)d_in[7];
    const float* wa_y = (const float*)d_in[8];
    const float* ba   = (const float*)d_in[9];

    char* ws = (char*)d_ws;
    _Float16* XW = (_Float16*)(ws + WS_XW);
    _Float16* W1 = (_Float16*)(ws + WS_W1);
    _Float16* W2 = (_Float16*)(ws + WS_W2);
    float* XA = (float*)(ws + WS_XA);
    unsigned int* Hbuf = (unsigned int*)(ws + WS_HBUF);
    float* PART = (float*)(ws + WS_PART);
    unsigned int* CNT = (unsigned int*)(ws + WS_CNT);

    float* out = (float*)d_out;
    float* yfin = out + (size_t)B_ * T_ * O_;

    hipMemsetAsync(CNT, 0, 2048, stream);
    hipLaunchKernelGGL(init_weights, dim3(2048), dim3(256), 0, stream,
                       ww_x, wb_x, ww_y, wb_y, W1, W2);
    hipLaunchKernelGGL(gemm1, dim3(4096), dim3(256), 0, stream, x, W1, bw, bb, XW);
    hipLaunchKernelGGL(xa_proj, dim3(8192), dim3(256), 0, stream, x, wa_x, ba, XA);
    hipFuncSetAttribute((const void*)scan_kernel,
                        hipFuncAttributeMaxDynamicSharedMemorySize, SMEM_BYTES);
    hipLaunchKernelGGL(scan_kernel, dim3(256), dim3(256), SMEM_BYTES, stream,
                       XW, XA, W2, wa_y, out, yfin, Hbuf, PART, CNT);
}

// Round 4
// 2252.669 us; speedup vs baseline: 1.3898x; 1.3898x over previous
//
#include <hip/hip_runtime.h>
#include <hip/hip_fp16.h>

// A-SNN forward: B=64, T=512, I=O=1024, A=3.
//   init_w1:  fp32->fp16 [ww_x;wb_x] for gemm1
//   gemm1:    XW[t*64+b][0:2048] = x @ [ww_x;wb_x]^T + bias   (MFMA 16x16x32 f16)
//   init_w2p: fragment-packed fp16 recurrent weights W2P[g][w][tile][ktl][lane][8]
//             rows 0..31 = ww_y(cols of group), 32..63 = wb_y, 64..66 = wa_y, 67..79 = 0
//   xa_proj:  XA = x @ wa_x^T + ba
//   scan:     256 WGs = 8 batch-domains x 32 col-groups; weights in VGPRs (K-split
//             across 4 waves); h exchanged via tagged u32 (fp16<<16 | t+1) polled
//             directly from L3 in MFMA fragment order; one LDS reduce + barrier/step.

#define B_ 64
#define T_ 512
#define I_ 1024
#define O_ 1024

typedef __attribute__((ext_vector_type(8))) _Float16 half8;
typedef __attribute__((ext_vector_type(4))) float f32x4;
typedef __attribute__((ext_vector_type(4))) float float4v;
typedef __attribute__((ext_vector_type(4))) unsigned int uint4v;

__device__ __forceinline__ float sigm_f(float x) { return 1.f / (1.f + __expf(-x)); }
__device__ __forceinline__ float tanh_f(float x) { return 1.f - 2.f / (1.f + __expf(2.f * x)); }

// ---------------- workspace layout (bytes) ----------------
#define WS_XW    0                 // [32768][2048] f16 = 134,217,728
#define WS_W1    134217728         // [2048][1024] f16 = 4,194,304 (dead after gemm1)
#define WS_W2P   134217728         // 2,621,440 halves = 5,242,880 B (overlays W1, written after gemm1)
#define WS_XA    139460608         // [32768][3] f32 = 393,216
#define WS_HBUF  139853824         // [2][64][1024] u32 = 524,288
#define HBUF_BYTES 524288
// total 140,378,112 (< proven 143,427,584)

// ======================= init: W1 =======================
__global__ void init_w1(const float* __restrict__ ww_x, const float* __restrict__ wb_x,
                        _Float16* __restrict__ W1) {
    const int total = 2048 * 1024;
    for (int idx = blockIdx.x * blockDim.x + threadIdx.x; idx < total;
         idx += gridDim.x * blockDim.x) {
        int n = idx >> 10, i = idx & 1023;
        float v = (n < 1024) ? ww_x[n * 1024 + i] : wb_x[(n - 1024) * 1024 + i];
        W1[idx] = (_Float16)v;
    }
}

// ======================= init: fragment-packed recurrent weights =======================
// idx = ((((g*4+w)*5 + tile)*8 + ktl)*64 + lane)*8 + j
// row r = tile*16 + (lane&15); k = w*256 + ktl*32 + (lane>>4)*8 + j
__global__ void init_w2p(const float* __restrict__ ww_y, const float* __restrict__ wb_y,
                         const float* __restrict__ wa_y, _Float16* __restrict__ W2P) {
    const int total = 32 * 4 * 5 * 8 * 64 * 8;  // 2,621,440
    for (int idx = blockIdx.x * blockDim.x + threadIdx.x; idx < total;
         idx += gridDim.x * blockDim.x) {
        int j = idx & 7;
        int lane = (idx >> 3) & 63;
        int ktl = (idx >> 9) & 7;
        int rest = idx >> 12;          // (g*4+w)*5 + tile
        int tile = rest % 5;
        int gw = rest / 5;
        int w = gw & 3, g = gw >> 2;
        int frow = lane & 15, fch = lane >> 4;
        int r = tile * 16 + frow;
        int k = w * 256 + ktl * 32 + fch * 8 + j;
        float v = 0.f;
        if (r < 32)      v = ww_y[(g * 32 + r) * 1024 + k];
        else if (r < 64) v = wb_y[(g * 32 + r - 32) * 1024 + k];
        else if (r < 67) v = wa_y[(r - 64) * 1024 + k];
        W2P[idx] = (_Float16)v;
    }
}

// ======================= gemm1: input projections =======================
__global__ __launch_bounds__(256) void gemm1(const float* __restrict__ x,
                                             const _Float16* __restrict__ W1,
                                             const float* __restrict__ bw,
                                             const float* __restrict__ bb,
                                             _Float16* __restrict__ XW) {
    __shared__ _Float16 At[2][128][40];
    __shared__ _Float16 Bt[2][128][40];
    const int tid = threadIdx.x;
    const int lane = tid & 63, wid = tid >> 6;
    const int wr = wid >> 1, wc = wid & 1;
    const int ntile = blockIdx.x & 15;
    const int mtile = blockIdx.x >> 4;
    const long m0 = (long)mtile * 128;
    const int n0 = ntile * 128;

    const int r = tid >> 1, hf = tid & 1;
    const int bidx = (int)((m0 + r) & 63);
    const int tt = (int)((m0 + r) >> 6);
    const float* xrow = x + ((size_t)bidx * T_ + tt) * I_ + hf * 16;
    const _Float16* brow = W1 + (size_t)(n0 + r) * 1024 + hf * 16;

    float4v av[4];
    uint4v bv[2];
    auto stage_regs = [&](int kt) {
        const float4v* pa = (const float4v*)(xrow + kt * 32);
        av[0] = pa[0]; av[1] = pa[1]; av[2] = pa[2]; av[3] = pa[3];
        const uint4v* pb = (const uint4v*)(brow + kt * 32);
        bv[0] = pb[0]; bv[1] = pb[1];
    };
    auto write_lds = [&](int buf) {
        union { _Float16 h[16]; half8 v[2]; } u;
        #pragma unroll
        for (int q = 0; q < 4; ++q)
            #pragma unroll
            for (int c = 0; c < 4; ++c) u.h[q * 4 + c] = (_Float16)av[q][c];
        half8* dA = (half8*)&At[buf][r][hf * 16];
        dA[0] = u.v[0]; dA[1] = u.v[1];
        uint4v* dB = (uint4v*)&Bt[buf][r][hf * 16];
        dB[0] = bv[0]; dB[1] = bv[1];
    };

    f32x4 acc[4][4];
    #pragma unroll
    for (int i = 0; i < 4; ++i)
        #pragma unroll
        for (int j = 0; j < 4; ++j) acc[i][j] = (f32x4){0.f, 0.f, 0.f, 0.f};

    const int frow = lane & 15, fch = lane >> 4;
    auto compute = [&](int buf) {
        half8 a[4], b[4];
        #pragma unroll
        for (int i = 0; i < 4; ++i)
            a[i] = *(const half8*)&At[buf][wr * 64 + i * 16 + frow][fch * 8];
        #pragma unroll
        for (int j = 0; j < 4; ++j)
            b[j] = *(const half8*)&Bt[buf][wc * 64 + j * 16 + frow][fch * 8];
        #pragma unroll
        for (int i = 0; i < 4; ++i)
            #pragma unroll
            for (int j = 0; j < 4; ++j)
                acc[i][j] = __builtin_amdgcn_mfma_f32_16x16x32_f16(a[i], b[j], acc[i][j], 0, 0, 0);
    };

    stage_regs(0);
    write_lds(0);
    __syncthreads();
    for (int kt = 0; kt < 32; ++kt) {
        const int cur = kt & 1;
        if (kt < 31) stage_regs(kt + 1);
        compute(cur);
        if (kt < 31) { write_lds(cur ^ 1); __syncthreads(); }
    }

    const int orow = (lane >> 4) * 4, ocol = lane & 15;
    #pragma unroll
    for (int j = 0; j < 4; ++j) {
        const int n = n0 + wc * 64 + j * 16 + ocol;
        const float bias = (n < 1024) ? bw[n] : bb[n - 1024];
        #pragma unroll
        for (int i = 0; i < 4; ++i) {
            const long mb = m0 + wr * 64 + i * 16 + orow;
            #pragma unroll
            for (int rr = 0; rr < 4; ++rr)
                XW[(size_t)(mb + rr) * 2048 + n] = (_Float16)(acc[i][j][rr] + bias);
        }
    }
}

// ======================= xa projection =======================
__global__ __launch_bounds__(256) void xa_proj(const float* __restrict__ x,
                                               const float* __restrict__ wa_x,
                                               const float* __restrict__ ba,
                                               float* __restrict__ XA) {
    const int wid = threadIdx.x >> 6, lane = threadIdx.x & 63;
    const long m = (long)blockIdx.x * 4 + wid;
    const int b = (int)(m & 63), t = (int)(m >> 6);
    const float4v* xr = (const float4v*)(x + ((size_t)b * T_ + t) * I_);
    const float4v* w0 = (const float4v*)(wa_x);
    const float4v* w1 = (const float4v*)(wa_x + 1024);
    const float4v* w2 = (const float4v*)(wa_x + 2048);
    float a0 = 0.f, a1 = 0.f, a2 = 0.f;
    #pragma unroll
    for (int j = 0; j < 4; ++j) {
        const int idx = j * 64 + lane;
        float4v xv = xr[idx];
        float4v v0 = w0[idx], v1 = w1[idx], v2 = w2[idx];
        a0 += xv[0] * v0[0] + xv[1] * v0[1] + xv[2] * v0[2] + xv[3] * v0[3];
        a1 += xv[0] * v1[0] + xv[1] * v1[1] + xv[2] * v1[2] + xv[3] * v1[3];
        a2 += xv[0] * v2[0] + xv[1] * v2[1] + xv[2] * v2[2] + xv[3] * v2[3];
    }
    #pragma unroll
    for (int mset = 32; mset >= 1; mset >>= 1) {
        a0 += __shfl_xor(a0, mset);
        a1 += __shfl_xor(a1, mset);
        a2 += __shfl_xor(a2, mset);
    }
    if (lane == 0) {
        XA[m * 3 + 0] = a0 + ba[0];
        XA[m * 3 + 1] = a1 + ba[1];
        XA[m * 3 + 2] = a2 + ba[2];
    }
}

// ======================= scan =======================
#define XOR4(v) ((v[0] ^ tg) | (v[1] ^ tg) | (v[2] ^ tg) | (v[3] ^ tg))
#define PK2(lo, hi) (((lo) >> 16) | ((hi) & 0xffff0000u))
#define PACKF(dst, A, Bv) { union { unsigned u[4]; half8 h; } uu; \
    uu.u[0] = PK2(A[0], A[1]); uu.u[1] = PK2(A[2], A[3]); \
    uu.u[2] = PK2(Bv[0], Bv[1]); uu.u[3] = PK2(Bv[2], Bv[3]); dst = uu.h; }

__global__ __launch_bounds__(256, 1) void scan_kernel(
    const _Float16* __restrict__ XW, const float* __restrict__ XA,
    const _Float16* __restrict__ W2P,
    float* __restrict__ out, float* __restrict__ yfin,
    unsigned int* __restrict__ Hbuf) {
    // [par][wave][tile][col16][row8 pad12] f32
    __shared__ __align__(16) float PR[2][4][5][16][12];

    const int tid = threadIdx.x;
    const int lane = tid & 63, w = tid >> 6;
    const int d = blockIdx.x & 7, g = blockIdx.x >> 3;
    const int b0 = d * 8, n0 = g * 32;
    const int bl = tid >> 5;       // 0..7 local batch (gate layout)
    const int nn = tid & 31;       // 0..31 local col
    const int frow = lane & 15, fch = lane >> 4;
    const int hi = lane >> 4, col = lane & 15;

    // -------- recurrent weights -> registers (fragment-packed) --------
    half8 Bf[5][8];
    {
        const _Float16* wp = W2P + ((size_t)(g * 4 + w) * 40 * 64 + lane) * 8;
        #pragma unroll
        for (int tile = 0; tile < 5; ++tile)
            #pragma unroll
            for (int ktl = 0; ktl < 8; ++ktl)
                Bf[tile][ktl] = *(const half8*)(wp + (size_t)(tile * 8 + ktl) * 512);
    }

    float y = 0.f;
    for (int t = 0; t < T_; ++t) {
        const int par = t & 1;
        f32x4 acc[5];
        #pragma unroll
        for (int tile = 0; tile < 5; ++tile) acc[tile] = (f32x4){0.f, 0.f, 0.f, 0.f};

        if (t > 0) {
            half8 af[8];
            #pragma unroll
            for (int f = 0; f < 8; ++f) af[f] = (half8)(_Float16)0.f;

            if (frow < 8) {
                const unsigned tg = (unsigned)t;  // h_{t-1} tagged with (t-1)+1 = t
                const unsigned* hp = Hbuf + ((size_t)((t - 1) & 1) * 64 + b0 + frow) * 1024
                                     + w * 256 + fch * 8;
                uint4v q0, q1, q2, q3, q4, q5, q6, q7, q8, q9, q10, q11, q12, q13, q14, q15;
                while (true) {
                    asm volatile(
                        "global_load_dwordx4 %0, %8, off sc0 sc1\n\t"
                        "global_load_dwordx4 %1, %8, off offset:16 sc0 sc1\n\t"
                        "global_load_dwordx4 %2, %8, off offset:128 sc0 sc1\n\t"
                        "global_load_dwordx4 %3, %8, off offset:144 sc0 sc1\n\t"
                        "global_load_dwordx4 %4, %8, off offset:256 sc0 sc1\n\t"
                        "global_load_dwordx4 %5, %8, off offset:272 sc0 sc1\n\t"
                        "global_load_dwordx4 %6, %8, off offset:384 sc0 sc1\n\t"
                        "global_load_dwordx4 %7, %8, off offset:400 sc0 sc1"
                        : "=&v"(q0), "=&v"(q1), "=&v"(q2), "=&v"(q3),
                          "=&v"(q4), "=&v"(q5), "=&v"(q6), "=&v"(q7)
                        : "v"(hp) : "memory");
                    asm volatile(
                        "global_load_dwordx4 %0, %8, off offset:512 sc0 sc1\n\t"
                        "global_load_dwordx4 %1, %8, off offset:528 sc0 sc1\n\t"
                        "global_load_dwordx4 %2, %8, off offset:640 sc0 sc1\n\t"
                        "global_load_dwordx4 %3, %8, off offset:656 sc0 sc1\n\t"
                        "global_load_dwordx4 %4, %8, off offset:768 sc0 sc1\n\t"
                        "global_load_dwordx4 %5, %8, off offset:784 sc0 sc1\n\t"
                        "global_load_dwordx4 %6, %8, off offset:896 sc0 sc1\n\t"
                        "global_load_dwordx4 %7, %8, off offset:912 sc0 sc1\n\t"
                        "s_waitcnt vmcnt(0)"
                        : "=&v"(q8), "=&v"(q9), "=&v"(q10), "=&v"(q11),
                          "=&v"(q12), "=&v"(q13), "=&v"(q14), "=&v"(q15)
                        : "v"(hp) : "memory");
                    unsigned bad = (XOR4(q0) | XOR4(q1) | XOR4(q2) | XOR4(q3)
                                  | XOR4(q4) | XOR4(q5) | XOR4(q6) | XOR4(q7)
                                  | XOR4(q8) | XOR4(q9) | XOR4(q10) | XOR4(q11)
                                  | XOR4(q12) | XOR4(q13) | XOR4(q14) | XOR4(q15)) & 0xffffu;
                    if (!__any((int)bad)) break;
                }
                PACKF(af[0], q0, q1);   PACKF(af[1], q2, q3);
                PACKF(af[2], q4, q5);   PACKF(af[3], q6, q7);
                PACKF(af[4], q8, q9);   PACKF(af[5], q10, q11);
                PACKF(af[6], q12, q13); PACKF(af[7], q14, q15);
            }
            #pragma unroll
            for (int f = 0; f < 8; ++f)
                #pragma unroll
                for (int tile = 0; tile < 5; ++tile)
                    acc[tile] = __builtin_amdgcn_mfma_f32_16x16x32_f16(af[f], Bf[tile][f],
                                                                       acc[tile], 0, 0, 0);
        }

        // gate inputs (latency hidden under reduce)
        const size_t mrow = (size_t)t * 64 + (size_t)(b0 + bl);
        const float xwv = (float)XW[mrow * 2048 + (n0 + nn)];
        const float xbv = (float)XW[mrow * 2048 + 1024 + (n0 + nn)];
        const float xa0 = XA[mrow * 3 + 0];
        const float xa1 = XA[mrow * 3 + 1];
        const float xa2 = XA[mrow * 3 + 2];

        // cross-wave K-reduce via LDS (rows 0..7 live in lanes 0..31)
        if (t > 0 && hi < 2) {
            #pragma unroll
            for (int tile = 0; tile < 5; ++tile)
                *(f32x4*)&PR[par][w][tile][col][hi * 4] = acc[tile];
        }
        __syncthreads();

        float gw = 0.f, gb = 0.f, pav = 0.f;
        if (t > 0) {
            const int tw = nn >> 4, c = nn & 15, ac = nn & 3;
            #pragma unroll
            for (int ww = 0; ww < 4; ++ww) {
                gw += PR[par][ww][tw][c][bl];
                gb += PR[par][ww][2 + tw][c][bl];
                pav += PR[par][ww][4][ac][bl];
            }
        }
        const float pa0 = __shfl(pav, (lane & 32) + 0);
        const float pa1 = __shfl(pav, (lane & 32) + 1);
        const float pa2 = __shfl(pav, (lane & 32) + 2);

        const float wv = sigm_f(xwv + gw);
        const float bgt = tanh_f(xbv + gb);
        const float wa0 = sigm_f(xa0 + pa0);
        const float wa1 = sigm_f(xa1 + pa1);
        const float wa2 = sigm_f(xa2 + pa2);
        y = wv * y + bgt;
        y = (y >= 0.f) ? y : 0.01f * y;
        const float th = tanh_f(y);
        const float sp = (y > 20.f) ? y : __logf(1.f + __expf(y));
        const float h = tanh_f(0.1f * (y * wa0 + th * wa1 + sp * wa2));

        // tagged h store (the signal IS the data), then out off the critical path
        _Float16 hh = (_Float16)h;
        const unsigned hu = ((unsigned)*(unsigned short*)&hh << 16) | (unsigned)(t + 1);
        __hip_atomic_store(&Hbuf[((size_t)par * 64 + b0 + bl) * 1024 + n0 + nn], hu,
                           __ATOMIC_RELAXED, __HIP_MEMORY_SCOPE_AGENT);
        out[((size_t)(b0 + bl) * T_ + t) * O_ + n0 + nn] = h;
    }
    yfin[(size_t)(b0 + bl) * O_ + n0 + nn] = y;
}

// ======================= launch =======================
extern "C" void kernel_launch(void* const* d_in, const int* in_sizes, int n_in,
                              void* d_out, int out_size, void* d_ws, size_t ws_size,
                              hipStream_t stream) {
    const float* x    = (const float*)d_in[0];
    const float* ww_x = (const float*)d_in[1];
    const float* ww_y = (const float*)d_in[2];
    const float* bw   = (const float*)d_in[3];
    const float* wb_x = (const float*)d_in[4];
    const float* wb_y = (const float*)d_in[5];
    const float* bb   = (const float*)d_in[6];
    const float* wa_x = (const float*)d_in[7];
    const float* wa_y = (const float*)d_in[8];
    const float* ba   = (const float*)d_in[9];

    char* ws = (char*)d_ws;
    _Float16* XW  = (_Float16*)(ws + WS_XW);
    _Float16* W1  = (_Float16*)(ws + WS_W1);
    _Float16* W2P = (_Float16*)(ws + WS_W2P);
    float* XA = (float*)(ws + WS_XA);
    unsigned int* Hbuf = (unsigned int*)(ws + WS_HBUF);

    float* out = (float*)d_out;
    float* yfin = out + (size_t)B_ * T_ * O_;

    hipMemsetAsync(Hbuf, 0, HBUF_BYTES, stream);
    hipLaunchKernelGGL(init_w1, dim3(2048), dim3(256), 0, stream, ww_x, wb_x, W1);
    hipLaunchKernelGGL(gemm1, dim3(4096), dim3(256), 0, stream, x, W1, bw, bb, XW);
    hipLaunchKernelGGL(init_w2p, dim3(1024), dim3(256), 0, stream, ww_y, wb_y, wa_y, W2P);
    hipLaunchKernelGGL(xa_proj, dim3(8192), dim3(256), 0, stream, x, wa_x, ba, XA);
    hipLaunchKernelGGL(scan_kernel, dim3(256), dim3(256), 0, stream,
                       XW, XA, W2P, out, yfin, Hbuf);
}

// Round 5
// 2011.591 us; speedup vs baseline: 1.5563x; 1.1198x over previous
//
#include <hip/hip_runtime.h>
#include <hip/hip_fp16.h>

// A-SNN forward: B=64, T=512, I=O=1024, A=3.
//   init_w1:  fp32->fp16 [ww_x;wb_x] for gemm1
//   gemm1:    XW[t*64+b][0:2048] = x @ [ww_x;wb_x]^T + bias   (MFMA 16x16x32 f16)
//   init_w2p: fragment-packed fp16 recurrent weights W2P[g][w][tile][ktl][lane][8]
//             rows 0..31 = ww_y(cols of group), 32..63 = wb_y, 64..66 = wa_y, 67..79 = 0
//   xa_proj:  XA = x @ wa_x^T + ba
//   scan:     256 WGs = 8 batch-domains x 32 col-groups; weights pinned in VGPRs
//             (K-split across 4 waves); h exchanged as plain fp16 + per-wave flags
//             (value t+1) at agent scope; consumers spin on an 8B flag load, then
//             bulk-load A-fragments once. One LDS reduce + one barrier per step.

#define B_ 64
#define T_ 512
#define I_ 1024
#define O_ 1024

typedef __attribute__((ext_vector_type(8))) _Float16 half8;
typedef __attribute__((ext_vector_type(4))) float f32x4;
typedef __attribute__((ext_vector_type(4))) float float4v;
typedef __attribute__((ext_vector_type(4))) unsigned int uint4v;
typedef __attribute__((ext_vector_type(2))) unsigned int uint2v;

__device__ __forceinline__ float sigm_f(float x) { return 1.f / (1.f + __expf(-x)); }
__device__ __forceinline__ float tanh_f(float x) { return 1.f - 2.f / (1.f + __expf(2.f * x)); }
__device__ __forceinline__ float h2f_bits(unsigned short u) {
    union { unsigned short s; _Float16 h; } x; x.s = u; return (float)x.h;
}

// ---------------- workspace layout (bytes) ----------------
#define WS_XW    0                 // [32768][2048] f16 = 134,217,728
#define WS_W1    134217728         // [2048][1024] f16 (dead after gemm1)
#define WS_W2P   134217728         // 2,621,440 halves = 5,242,880 B (overlays W1)
#define WS_XA    139460608         // [32768][3] f32 = 393,216
#define WS_HBUF  139853824         // [2][64][1024] f16 = 262,144
#define WS_FLG   140115968         // [2][8][128] u32 = 8,192
#define FLG_BYTES 8192
// total 140,124,160

// ======================= init: W1 =======================
__global__ void init_w1(const float* __restrict__ ww_x, const float* __restrict__ wb_x,
                        _Float16* __restrict__ W1) {
    const int total = 2048 * 1024;
    for (int idx = blockIdx.x * blockDim.x + threadIdx.x; idx < total;
         idx += gridDim.x * blockDim.x) {
        int n = idx >> 10, i = idx & 1023;
        float v = (n < 1024) ? ww_x[n * 1024 + i] : wb_x[(n - 1024) * 1024 + i];
        W1[idx] = (_Float16)v;
    }
}

// ======================= init: fragment-packed recurrent weights =======================
// idx = ((((g*4+w)*5 + tile)*8 + ktl)*64 + lane)*8 + j
// row r = tile*16 + (lane&15); k = w*256 + ktl*32 + (lane>>4)*8 + j
__global__ void init_w2p(const float* __restrict__ ww_y, const float* __restrict__ wb_y,
                         const float* __restrict__ wa_y, _Float16* __restrict__ W2P) {
    const int total = 32 * 4 * 5 * 8 * 64 * 8;  // 2,621,440
    for (int idx = blockIdx.x * blockDim.x + threadIdx.x; idx < total;
         idx += gridDim.x * blockDim.x) {
        int j = idx & 7;
        int lane = (idx >> 3) & 63;
        int ktl = (idx >> 9) & 7;
        int rest = idx >> 12;          // (g*4+w)*5 + tile
        int tile = rest % 5;
        int gw = rest / 5;
        int w = gw & 3, g = gw >> 2;
        int frow = lane & 15, fch = lane >> 4;
        int r = tile * 16 + frow;
        int k = w * 256 + ktl * 32 + fch * 8 + j;
        float v = 0.f;
        if (r < 32)      v = ww_y[(g * 32 + r) * 1024 + k];
        else if (r < 64) v = wb_y[(g * 32 + r - 32) * 1024 + k];
        else if (r < 67) v = wa_y[(r - 64) * 1024 + k];
        W2P[idx] = (_Float16)v;
    }
}

// ======================= gemm1: input projections =======================
__global__ __launch_bounds__(256) void gemm1(const float* __restrict__ x,
                                             const _Float16* __restrict__ W1,
                                             const float* __restrict__ bw,
                                             const float* __restrict__ bb,
                                             _Float16* __restrict__ XW) {
    __shared__ _Float16 At[2][128][40];
    __shared__ _Float16 Bt[2][128][40];
    const int tid = threadIdx.x;
    const int lane = tid & 63, wid = tid >> 6;
    const int wr = wid >> 1, wc = wid & 1;
    const int ntile = blockIdx.x & 15;
    const int mtile = blockIdx.x >> 4;
    const long m0 = (long)mtile * 128;
    const int n0 = ntile * 128;

    const int r = tid >> 1, hf = tid & 1;
    const int bidx = (int)((m0 + r) & 63);
    const int tt = (int)((m0 + r) >> 6);
    const float* xrow = x + ((size_t)bidx * T_ + tt) * I_ + hf * 16;
    const _Float16* brow = W1 + (size_t)(n0 + r) * 1024 + hf * 16;

    float4v av[4];
    uint4v bv[2];
    auto stage_regs = [&](int kt) {
        const float4v* pa = (const float4v*)(xrow + kt * 32);
        av[0] = pa[0]; av[1] = pa[1]; av[2] = pa[2]; av[3] = pa[3];
        const uint4v* pb = (const uint4v*)(brow + kt * 32);
        bv[0] = pb[0]; bv[1] = pb[1];
    };
    auto write_lds = [&](int buf) {
        union { _Float16 h[16]; half8 v[2]; } u;
        #pragma unroll
        for (int q = 0; q < 4; ++q)
            #pragma unroll
            for (int c = 0; c < 4; ++c) u.h[q * 4 + c] = (_Float16)av[q][c];
        half8* dA = (half8*)&At[buf][r][hf * 16];
        dA[0] = u.v[0]; dA[1] = u.v[1];
        uint4v* dB = (uint4v*)&Bt[buf][r][hf * 16];
        dB[0] = bv[0]; dB[1] = bv[1];
    };

    f32x4 acc[4][4];
    #pragma unroll
    for (int i = 0; i < 4; ++i)
        #pragma unroll
        for (int j = 0; j < 4; ++j) acc[i][j] = (f32x4){0.f, 0.f, 0.f, 0.f};

    const int frow = lane & 15, fch = lane >> 4;
    auto compute = [&](int buf) {
        half8 a[4], b[4];
        #pragma unroll
        for (int i = 0; i < 4; ++i)
            a[i] = *(const half8*)&At[buf][wr * 64 + i * 16 + frow][fch * 8];
        #pragma unroll
        for (int j = 0; j < 4; ++j)
            b[j] = *(const half8*)&Bt[buf][wc * 64 + j * 16 + frow][fch * 8];
        #pragma unroll
        for (int i = 0; i < 4; ++i)
            #pragma unroll
            for (int j = 0; j < 4; ++j)
                acc[i][j] = __builtin_amdgcn_mfma_f32_16x16x32_f16(a[i], b[j], acc[i][j], 0, 0, 0);
    };

    stage_regs(0);
    write_lds(0);
    __syncthreads();
    for (int kt = 0; kt < 32; ++kt) {
        const int cur = kt & 1;
        if (kt < 31) stage_regs(kt + 1);
        compute(cur);
        if (kt < 31) { write_lds(cur ^ 1); __syncthreads(); }
    }

    const int orow = (lane >> 4) * 4, ocol = lane & 15;
    #pragma unroll
    for (int j = 0; j < 4; ++j) {
        const int n = n0 + wc * 64 + j * 16 + ocol;
        const float bias = (n < 1024) ? bw[n] : bb[n - 1024];
        #pragma unroll
        for (int i = 0; i < 4; ++i) {
            const long mb = m0 + wr * 64 + i * 16 + orow;
            #pragma unroll
            for (int rr = 0; rr < 4; ++rr)
                XW[(size_t)(mb + rr) * 2048 + n] = (_Float16)(acc[i][j][rr] + bias);
        }
    }
}

// ======================= xa projection =======================
__global__ __launch_bounds__(256) void xa_proj(const float* __restrict__ x,
                                               const float* __restrict__ wa_x,
                                               const float* __restrict__ ba,
                                               float* __restrict__ XA) {
    const int wid = threadIdx.x >> 6, lane = threadIdx.x & 63;
    const long m = (long)blockIdx.x * 4 + wid;
    const int b = (int)(m & 63), t = (int)(m >> 6);
    const float4v* xr = (const float4v*)(x + ((size_t)b * T_ + t) * I_);
    const float4v* w0 = (const float4v*)(wa_x);
    const float4v* w1 = (const float4v*)(wa_x + 1024);
    const float4v* w2 = (const float4v*)(wa_x + 2048);
    float a0 = 0.f, a1 = 0.f, a2 = 0.f;
    #pragma unroll
    for (int j = 0; j < 4; ++j) {
        const int idx = j * 64 + lane;
        float4v xv = xr[idx];
        float4v v0 = w0[idx], v1 = w1[idx], v2 = w2[idx];
        a0 += xv[0] * v0[0] + xv[1] * v0[1] + xv[2] * v0[2] + xv[3] * v0[3];
        a1 += xv[0] * v1[0] + xv[1] * v1[1] + xv[2] * v1[2] + xv[3] * v1[3];
        a2 += xv[0] * v2[0] + xv[1] * v2[1] + xv[2] * v2[2] + xv[3] * v2[3];
    }
    #pragma unroll
    for (int mset = 32; mset >= 1; mset >>= 1) {
        a0 += __shfl_xor(a0, mset);
        a1 += __shfl_xor(a1, mset);
        a2 += __shfl_xor(a2, mset);
    }
    if (lane == 0) {
        XA[m * 3 + 0] = a0 + ba[0];
        XA[m * 3 + 1] = a1 + ba[1];
        XA[m * 3 + 2] = a2 + ba[2];
    }
}

// ======================= scan =======================
__global__ __launch_bounds__(256, 1) void scan_kernel(
    const _Float16* __restrict__ XW, const float* __restrict__ XA,
    const _Float16* __restrict__ W2P,
    float* __restrict__ out, float* __restrict__ yfin,
    unsigned int* __restrict__ Hbuf, unsigned int* __restrict__ FLG) {
    // [par][wave][tile][col16][row8 pad12] f32
    __shared__ __align__(16) float PR[2][4][5][16][12];

    const int tid = threadIdx.x;
    const int lane = tid & 63, w = tid >> 6;
    const int d = blockIdx.x & 7, g = blockIdx.x >> 3;
    const int b0 = d * 8, n0 = g * 32;
    const int bl = tid >> 5;       // 0..7 local batch (gate layout)
    const int nn = tid & 31;       // 0..31 local col
    const int frow = lane & 15, fch = lane >> 4;
    const int hi = lane >> 4, col = lane & 15;

    // -------- recurrent weights -> registers (fragment-packed, pinned) --------
    half8 Bf[5][8];
    {
        const _Float16* wp = W2P + ((size_t)(g * 4 + w) * 40 * 64 + lane) * 8;
        #pragma unroll
        for (int tile = 0; tile < 5; ++tile)
            #pragma unroll
            for (int ktl = 0; ktl < 8; ++ktl)
                Bf[tile][ktl] = *(const half8*)(wp + (size_t)(tile * 8 + ktl) * 512);
    }
    #pragma unroll
    for (int tile = 0; tile < 5; ++tile)
        #pragma unroll
        for (int ktl = 0; ktl < 8; ++ktl)
            asm volatile("" : "+v"(Bf[tile][ktl]));   // pin in VGPRs (defeat remat)

    uint4v aq[8];
    #pragma unroll
    for (int f = 0; f < 8; ++f) aq[f] = (uint4v){0u, 0u, 0u, 0u};

    // gate-input prefetch pointers (per-thread)
    const unsigned short* xwp = (const unsigned short*)XW + (size_t)(b0 + bl) * 2048 + n0 + nn;
    const unsigned short* xbp = xwp + 1024;
    const float* xap = XA + (size_t)(b0 + bl) * 3;

    unsigned short c_xw = xwp[0], c_xb = xbp[0];
    float c_xa0 = xap[0], c_xa1 = xap[1], c_xa2 = xap[2];
    unsigned short n_xw = 0, n_xb = 0;
    float n_xa0 = 0.f, n_xa1 = 0.f, n_xa2 = 0.f;

    const _Float16* Hh = (const _Float16*)Hbuf;

    float y = 0.f;
    for (int t = 0; t < T_; ++t) {
        const int par = t & 1;
        f32x4 acc[5];
        #pragma unroll
        for (int tile = 0; tile < 5; ++tile) acc[tile] = (f32x4){0.f, 0.f, 0.f, 0.f};

        if (t > 0) {
            const int parp = (t - 1) & 1;
            // ---- slim flag poll: 8B per lane per retry ----
            {
                const unsigned need = (unsigned)t;
                const unsigned* fp2 = FLG + ((size_t)parp * 8 + d) * 128 + (lane << 1);
                uint2v fv;
                do {
                    asm volatile("global_load_dwordx2 %0, %1, off sc0 sc1\n\t"
                                 "s_waitcnt vmcnt(0)"
                                 : "=v"(fv) : "v"(fp2) : "memory");
                } while (__any((int)(fv[0] < need || fv[1] < need)));
            }
            // ---- bulk A-fragment load (plain fp16, MFMA layout) ----
            if (frow < 8) {
                const _Float16* hp = Hh + ((size_t)parp * 64 + b0 + frow) * 1024
                                     + w * 256 + fch * 8;
                asm volatile(
                    "global_load_dwordx4 %0, %8, off sc0 sc1\n\t"
                    "global_load_dwordx4 %1, %8, off offset:64 sc0 sc1\n\t"
                    "global_load_dwordx4 %2, %8, off offset:128 sc0 sc1\n\t"
                    "global_load_dwordx4 %3, %8, off offset:192 sc0 sc1\n\t"
                    "global_load_dwordx4 %4, %8, off offset:256 sc0 sc1\n\t"
                    "global_load_dwordx4 %5, %8, off offset:320 sc0 sc1\n\t"
                    "global_load_dwordx4 %6, %8, off offset:384 sc0 sc1\n\t"
                    "global_load_dwordx4 %7, %8, off offset:448 sc0 sc1\n\t"
                    "s_waitcnt vmcnt(0)"
                    : "=&v"(aq[0]), "=&v"(aq[1]), "=&v"(aq[2]), "=&v"(aq[3]),
                      "=&v"(aq[4]), "=&v"(aq[5]), "=&v"(aq[6]), "=&v"(aq[7])
                    : "v"(hp) : "memory");
            }
            #pragma unroll
            for (int f = 0; f < 8; ++f) {
                union { uint4v u; half8 h; } ua;
                ua.u = aq[f];
                #pragma unroll
                for (int tile = 0; tile < 5; ++tile)
                    acc[tile] = __builtin_amdgcn_mfma_f32_16x16x32_f16(ua.h, Bf[tile][f],
                                                                       acc[tile], 0, 0, 0);
            }
        }

        // cross-wave K-reduce via LDS (C rows 0..7 live in lanes 0..31)
        if (t > 0 && hi < 2) {
            #pragma unroll
            for (int tile = 0; tile < 5; ++tile)
                *(f32x4*)&PR[par][w][tile][col][hi * 4] = acc[tile];
        }
        __syncthreads();

        float gw = 0.f, gb = 0.f, pav = 0.f;
        if (t > 0) {
            const int tw = nn >> 4, c = nn & 15, ac = nn & 3;
            #pragma unroll
            for (int ww = 0; ww < 4; ++ww) {
                gw += PR[par][ww][tw][c][bl];
                gb += PR[par][ww][2 + tw][c][bl];
                pav += PR[par][ww][4][ac][bl];
            }
        }
        const float pa0 = __shfl(pav, (lane & 32) + 0);
        const float pa1 = __shfl(pav, (lane & 32) + 1);
        const float pa2 = __shfl(pav, (lane & 32) + 2);

        const float wv = sigm_f(h2f_bits(c_xw) + gw);
        const float bgt = tanh_f(h2f_bits(c_xb) + gb);
        const float wa0 = sigm_f(c_xa0 + pa0);
        const float wa1 = sigm_f(c_xa1 + pa1);
        const float wa2 = sigm_f(c_xa2 + pa2);
        y = wv * y + bgt;
        y = (y >= 0.f) ? y : 0.01f * y;
        const float th = tanh_f(y);
        const float sp = (y > 20.f) ? y : __logf(1.f + __expf(y));
        const float h = tanh_f(0.1f * (y * wa0 + th * wa1 + sp * wa2));

        // ---- h store (plain fp16 pairs, agent scope) ----
        {
            _Float16 hh = (_Float16)h;
            union { _Float16 x; unsigned short s; } hb; hb.x = hh;
            unsigned hu = hb.s;
            const unsigned partner = (unsigned)__shfl_xor((int)hu, 1);
            if (!(nn & 1)) {
                const unsigned packed = hu | (partner << 16);
                __hip_atomic_store(&Hbuf[(size_t)(par * 64 + b0 + bl) * 512 + ((n0 + nn) >> 1)],
                                   packed, __ATOMIC_RELAXED, __HIP_MEMORY_SCOPE_AGENT);
            }
        }
        // per-wave release: wait own stores acked, then publish flag t+1
        asm volatile("s_waitcnt vmcnt(0)" ::: "memory");
        if (lane == 0)
            __hip_atomic_store(&FLG[((size_t)par * 8 + d) * 128 + (g << 2) + w],
                               (unsigned)(t + 1), __ATOMIC_RELAXED, __HIP_MEMORY_SCOPE_AGENT);

        // off the critical path: result store + next-step gate-input prefetch
        out[((size_t)(b0 + bl) * T_ + t) * O_ + n0 + nn] = h;
        if (t + 1 < T_) {
            const size_t o = (size_t)(t + 1) * 131072;
            n_xw = xwp[o];
            n_xb = xbp[o];
            const float* xa = xap + (size_t)(t + 1) * 192;
            n_xa0 = xa[0]; n_xa1 = xa[1]; n_xa2 = xa[2];
        }
        c_xw = n_xw; c_xb = n_xb;
        c_xa0 = n_xa0; c_xa1 = n_xa1; c_xa2 = n_xa2;
    }
    yfin[(size_t)(b0 + bl) * O_ + n0 + nn] = y;
}

// ======================= launch =======================
extern "C" void kernel_launch(void* const* d_in, const int* in_sizes, int n_in,
                              void* d_out, int out_size, void* d_ws, size_t ws_size,
                              hipStream_t stream) {
    const float* x    = (const float*)d_in[0];
    const float* ww_x = (const float*)d_in[1];
    const float* ww_y = (const float*)d_in[2];
    const float* bw   = (const float*)d_in[3];
    const float* wb_x = (const float*)d_in[4];
    const float* wb_y = (const float*)d_in[5];
    const float* bb   = (const float*)d_in[6];
    const float* wa_x = (const float*)d_in[7];
    const float* wa_y = (const float*)d_in[8];
    const float* ba   = (const float*)d_in[9];

    char* ws = (char*)d_ws;
    _Float16* XW  = (_Float16*)(ws + WS_XW);
    _Float16* W1  = (_Float16*)(ws + WS_W1);
    _Float16* W2P = (_Float16*)(ws + WS_W2P);
    float* XA = (float*)(ws + WS_XA);
    unsigned int* Hbuf = (unsigned int*)(ws + WS_HBUF);
    unsigned int* FLG  = (unsigned int*)(ws + WS_FLG);

    float* out = (float*)d_out;
    float* yfin = out + (size_t)B_ * T_ * O_;

    hipMemsetAsync(FLG, 0, FLG_BYTES, stream);
    hipLaunchKernelGGL(init_w1, dim3(2048), dim3(256), 0, stream, ww_x, wb_x, W1);
    hipLaunchKernelGGL(gemm1, dim3(4096), dim3(256), 0, stream, x, W1, bw, bb, XW);
    hipLaunchKernelGGL(init_w2p, dim3(1024), dim3(256), 0, stream, ww_y, wb_y, wa_y, W2P);
    hipLaunchKernelGGL(xa_proj, dim3(8192), dim3(256), 0, stream, x, wa_x, ba, XA);
    hipLaunchKernelGGL(scan_kernel, dim3(256), dim3(256), 0, stream,
                       XW, XA, W2P, out, yfin, Hbuf, FLG);
}